// Round 7
// baseline (335.018 us; speedup 1.0000x reference)
//
#include <hip/hip_runtime.h>
#include <math.h>

// Problem constants
#define NB 32768
#define NC 100
#define NK 8
#define ND 512
#define ALPHA 22.0f      // Neumann split: Ahat = ALPHA*(I - M); eig(Ahat) in [19.8, ~24.3]
#define NEU_ITERS 12
// Pipeline (7 launches):
//  k_hn         hnb = bf16(h/||h||)                     [32768,512]
//  k_prep_class Pn/centers/centersT/b_same + Bp proto rows (bf16)
//  k_csbopp     bvec = b_same - wo*(csum - center)
//  k_T1M        T1[j][i] = centers_i . X_j  (j=0..999)  + M from center rows
//  k_T2neu      T2 = Ahat^{-1} T1 via Neumann
//  k_solveW     per class ridge solve -> Bp W_hi/W_lo rows
//  k_main_mfma  256x160 block, 32x32x16 MFMA, barrier-free K-loop with direct
//               global fragment loads (no LDS staging), fused softmax epilogue

typedef __attribute__((ext_vector_type(8))) short short8;
typedef __attribute__((ext_vector_type(4))) float f32x4;
typedef __attribute__((ext_vector_type(16))) float f32x16;

__device__ __forceinline__ float warpReduceSum(float v) {
#pragma unroll
    for (int off = 32; off > 0; off >>= 1) v += __shfl_xor(v, off);
    return v;
}

__device__ float blockReduceSum256(float v, float* red) {
    int tid = threadIdx.x;
    v = warpReduceSum(v);
    __syncthreads();
    if ((tid & 63) == 0) red[tid >> 6] = v;
    __syncthreads();
    return red[0] + red[1] + red[2] + red[3];
}

__device__ __forceinline__ unsigned short f2bf(float x) {
    unsigned u = __float_as_uint(x);
    u = (u + 0x7FFFu + ((u >> 16) & 1u)) >> 16;
    return (unsigned short)u;
}
__device__ __forceinline__ float bf2f(unsigned short h) {
    return __uint_as_float(((unsigned)h) << 16);
}

// ------------------------- prep kernels (fp32) -------------------------

__global__ void k_prep_class(const float* __restrict__ protos, float* __restrict__ X,
                             float* __restrict__ centersT, unsigned short* __restrict__ Bp) {
    __shared__ float red[4];
    int c = blockIdx.x;
    int tid = threadIdx.x;
    const float eps = 1e-8f;
    float pv0[NK], pv1[NK];
#pragma unroll
    for (int k = 0; k < NK; ++k) {
        pv0[k] = protos[(c * NK + k) * ND + tid];
        pv1[k] = protos[(c * NK + k) * ND + tid + 256];
    }
    float sv0 = 0.f, sv1 = 0.f;
#pragma unroll
    for (int k = 0; k < NK; ++k) {
        float ss = blockReduceSum256(pv0[k] * pv0[k] + pv1[k] * pv1[k], red);
        float inv = 1.0f / fmaxf(sqrtf(ss), eps);
        pv0[k] *= inv; pv1[k] *= inv;
        X[(c * NK + k) * ND + tid] = pv0[k];
        X[(c * NK + k) * ND + tid + 256] = pv1[k];
        Bp[(size_t)(c * 10 + k) * ND + tid] = f2bf(pv0[k]);
        Bp[(size_t)(c * 10 + k) * ND + tid + 256] = f2bf(pv1[k]);
        sv0 += pv0[k]; sv1 += pv1[k];
    }
    float ssum = blockReduceSum256(sv0 * sv0 + sv1 * sv1, red);
    float mnorm = sqrtf(ssum) * 0.125f;
    float cinv = 0.125f / fmaxf(mnorm, eps);
    float* centers = X + 800 * ND;
    float c0 = sv0 * cinv, c1 = sv1 * cinv;
    centers[c * ND + tid] = c0;
    centers[c * ND + tid + 256] = c1;
    centersT[tid * NC + c] = c0;
    centersT[(tid + 256) * NC + c] = c1;
    const float ws = 0.5f / 8.0f;
    float* bvec = X + 900 * ND;
    bvec[c * ND + tid] = ws * sv0;
    bvec[c * ND + tid + 256] = ws * sv1;
}

__global__ void k_csbopp(float* __restrict__ X) {
    int c = blockIdx.x, tid = threadIdx.x;
    const float wo = 0.5f / 99.0f;
    const float* centers = X + 800 * ND;
    float* bvec = X + 900 * ND;
#pragma unroll
    for (int h = 0; h < 2; ++h) {
        int d = tid + h * 256;
        float s = 0.f;
#pragma unroll 4
        for (int i = 0; i < NC; ++i) s += centers[i * ND + d];
        bvec[c * ND + d] -= wo * (s - centers[c * ND + d]);
    }
}

__global__ __launch_bounds__(256) void k_T1M(const float* __restrict__ X,
                                             const float* __restrict__ centersT,
                                             float* __restrict__ T1, float* __restrict__ M) {
    __shared__ float xs[4][ND];
    int tid = threadIdx.x;
    int wave = tid >> 6, lane = tid & 63;
    int j = blockIdx.x * 4 + wave;
    reinterpret_cast<float4*>(xs[wave])[lane * 2] =
        reinterpret_cast<const float4*>(X + (size_t)j * ND)[lane * 2];
    reinterpret_cast<float4*>(xs[wave])[lane * 2 + 1] =
        reinterpret_cast<const float4*>(X + (size_t)j * ND)[lane * 2 + 1];
    __syncthreads();
    int i0 = lane, i1 = lane + 64;
    int i1c = (i1 < NC) ? i1 : 0;
    float s0 = 0.f, s1 = 0.f;
#pragma unroll 8
    for (int d = 0; d < ND; ++d) {
        float xv = xs[wave][d];
        s0 = fmaf(xv, centersT[d * NC + i0], s0);
        s1 = fmaf(xv, centersT[d * NC + i1c], s1);
    }
    T1[j * NC + i0] = s0;
    if (i1 < NC) T1[j * NC + i1] = s1;
    if (j >= 800 && j < 900) {
        int ci = j - 800;
        float a0 = s0 + ((i0 == ci) ? 19.8f : 0.f);
        M[ci * NC + i0] = ((i0 == ci) ? 1.f : 0.f) - a0 * (1.0f / ALPHA);
        if (i1 < NC) {
            float a1 = s1 + ((i1 == ci) ? 19.8f : 0.f);
            M[ci * NC + i1] = ((i1 == ci) ? 1.f : 0.f) - a1 * (1.0f / ALPHA);
        }
    }
}

__global__ __launch_bounds__(256) void k_T2neu(const float* __restrict__ M,
                                               const float* __restrict__ T1,
                                               float* __restrict__ T2) {
    __shared__ float Msh[NC * 108];
    __shared__ float pbuf[2][4][104];
    int tid = threadIdx.x;
    int wave = tid >> 6, lane = tid & 63;
    int j = blockIdx.x * 4 + wave;
    for (int idx = tid; idx < NC * NC; idx += 256) {
        int i = idx / NC, m = idx - i * NC;
        Msh[i * 108 + m] = M[idx];
    }
    int i0 = lane;
    int i1 = lane + 64;
    int i1c = (i1 < NC) ? i1 : 0;
    float t0 = T1[j * NC + i0];
    float t1v = (i1 < NC) ? T1[j * NC + i1] : 0.f;
    float s0 = t0, s1 = t1v;
    pbuf[0][wave][i0] = t0;
    if (i1 < NC) pbuf[0][wave][i1] = t1v;
    __syncthreads();
    int cur = 0;
    for (int it = 0; it < NEU_ITERS; ++it) {
        const float* p = pbuf[cur][wave];
        float y0 = 0.f, y1 = 0.f;
#pragma unroll 5
        for (int m = 0; m < NC; m += 4) {
            float4 pv = *reinterpret_cast<const float4*>(p + m);
            float4 a0 = *reinterpret_cast<const float4*>(&Msh[i0 * 108 + m]);
            float4 a1 = *reinterpret_cast<const float4*>(&Msh[i1c * 108 + m]);
            y0 = fmaf(a0.x, pv.x, y0); y0 = fmaf(a0.y, pv.y, y0);
            y0 = fmaf(a0.z, pv.z, y0); y0 = fmaf(a0.w, pv.w, y0);
            y1 = fmaf(a1.x, pv.x, y1); y1 = fmaf(a1.y, pv.y, y1);
            y1 = fmaf(a1.z, pv.z, y1); y1 = fmaf(a1.w, pv.w, y1);
        }
        s0 += y0; s1 += y1;
        int nxt = cur ^ 1;
        pbuf[nxt][wave][i0] = y0;
        if (i1 < NC) pbuf[nxt][wave][i1] = y1;
        cur = nxt;
    }
    T2[j * NC + i0] = s0 * (1.0f / ALPHA);
    if (i1 < NC) T2[j * NC + i1] = s1 * (1.0f / ALPHA);
}

__global__ __launch_bounds__(256) void k_solveW(const float* __restrict__ X,
                                                const float* __restrict__ T1,
                                                const float* __restrict__ T2,
                                                unsigned short* __restrict__ Bp) {
    int c = blockIdx.x, tid = threadIdx.x;
    if (c >= NC) {  // zero pad slots 100..111
        uint4 z = {0, 0, 0, 0};
        for (int idx = tid; idx < 10 * ND / 8; idx += 256)
            reinterpret_cast<uint4*>(Bp + (size_t)c * 10 * ND)[idx] = z;
        return;
    }
    __shared__ float Xs[10 * 516];
    __shared__ float T1s[10 * 104];
    __shared__ float T2s[10 * 104];
    __shared__ float G[10][10];
    __shared__ float SL[9 * 10];
    __shared__ float zL[9];
    __shared__ float q[104];
    for (int idx = tid; idx < 10 * 128; idx += 256) {
        int a = idx >> 7, p = idx & 127;
        int row = (a < 8) ? (c * 8 + a) : ((a == 8) ? (800 + c) : (900 + c));
        reinterpret_cast<float4*>(&Xs[a * 516])[p] =
            reinterpret_cast<const float4*>(X + (size_t)row * ND)[p];
    }
    for (int idx = tid; idx < 10 * NC; idx += 256) {
        int a = idx / NC, i = idx - a * NC;
        int row = (a < 8) ? (c * 8 + a) : ((a == 8) ? (800 + c) : (900 + c));
        T1s[a * 104 + i] = T1[row * NC + i];
        T2s[a * 104 + i] = T2[row * NC + i];
    }
    __syncthreads();
    if (tid < 100) {
        int a = tid / 10, b = tid - (tid / 10) * 10;
        float s = 0.f;
        for (int d = 0; d < ND; ++d) s += Xs[a * 516 + d] * Xs[b * 516 + d];
        G[a][b] = s;
    }
    __syncthreads();
    if (tid < 90) {
        int a = tid / 10, b = tid - (tid / 10) * 10;
        float s = 0.f;
#pragma unroll 4
        for (int i = 0; i < NC; ++i) s += T1s[a * 104 + i] * T2s[b * 104 + i];
        float val = (G[a][b] - s) * 10.0f;   // 1/ridge
        if (b == a) val += (a < 8) ? 16.0f : -198.0f;  // D^{-1}
        SL[tid] = val;
    }
    __syncthreads();
    if (tid == 0) {
        for (int p = 0; p < 9; ++p) {
            int best = p; float bv = fabsf(SL[p * 10 + p]);
            for (int r = p + 1; r < 9; ++r) {
                float v = fabsf(SL[r * 10 + p]);
                if (v > bv) { bv = v; best = r; }
            }
            if (best != p)
                for (int j = p; j < 10; ++j) {
                    float t = SL[p * 10 + j]; SL[p * 10 + j] = SL[best * 10 + j]; SL[best * 10 + j] = t;
                }
            float ip = 1.0f / SL[p * 10 + p];
            for (int r = p + 1; r < 9; ++r) {
                float f = SL[r * 10 + p] * ip;
                for (int j = p; j < 10; ++j) SL[r * 10 + j] -= f * SL[p * 10 + j];
            }
        }
        for (int p = 8; p >= 0; --p) {
            float s = SL[p * 10 + 9];
            for (int j = p + 1; j < 9; ++j) s -= SL[p * 10 + j] * zL[j];
            zL[p] = s / SL[p * 10 + p];
        }
    }
    __syncthreads();
    if (tid < NC) {
        float s = T2s[9 * 104 + tid];
#pragma unroll
        for (int a = 0; a < 9; ++a) s -= zL[a] * T2s[a * 104 + tid];
        q[tid] = s;
    }
    __syncthreads();
    const float* centers = X + 800 * ND;
#pragma unroll
    for (int h = 0; h < 2; ++h) {
        int d = tid + h * 256;
        float u = Xs[9 * 516 + d];
#pragma unroll
        for (int a = 0; a < 9; ++a) u -= zL[a] * Xs[a * 516 + d];
        float s = 0.f;
#pragma unroll 4
        for (int i = 0; i < NC; ++i) s = fmaf(centers[i * ND + d], q[i], s);
        float w = (u - s) * 10.0f;
        unsigned short hi = f2bf(w);
        Bp[(size_t)(c * 10 + 8) * ND + d] = hi;
        Bp[(size_t)(c * 10 + 9) * ND + d] = f2bf(w - bf2f(hi));
    }
}

// ------------------------- bf16 input normalization -------------------------

__global__ void k_hn(const float* __restrict__ h, unsigned short* __restrict__ hnb) {
    int tid = threadIdx.x;
    int wave = tid >> 6, lane = tid & 63;
    int r = blockIdx.x * 4 + wave;
    const float4* hp = reinterpret_cast<const float4*>(h + (size_t)r * ND);
    float4 v0 = hp[lane * 2];
    float4 v1 = hp[lane * 2 + 1];
    float s = v0.x * v0.x + v0.y * v0.y + v0.z * v0.z + v0.w * v0.w
            + v1.x * v1.x + v1.y * v1.y + v1.z * v1.z + v1.w * v1.w;
    s = warpReduceSum(s);
    float inv = 1.0f / fmaxf(sqrtf(s), 1e-8f);
    uint4 o;
    o.x = (unsigned)f2bf(v0.x * inv) | ((unsigned)f2bf(v0.y * inv) << 16);
    o.y = (unsigned)f2bf(v0.z * inv) | ((unsigned)f2bf(v0.w * inv) << 16);
    o.z = (unsigned)f2bf(v1.x * inv) | ((unsigned)f2bf(v1.y * inv) << 16);
    o.w = (unsigned)f2bf(v1.z * inv) | ((unsigned)f2bf(v1.w * inv) << 16);
    reinterpret_cast<uint4*>(hnb + (size_t)r * ND)[lane] = o;
}

// ------------------------- main MFMA GEMM + fused epilogue -------------------------
// Block 256 rows x 160 cols; 4 waves, each 2 row-tiles x 5 col-tiles of 32x32x16.
// K-loop is barrier-free: A and B fragments loaded straight from global (L1/L2-
// served; A rows XCD-localized by swizzle, B 1.15 MB L2-resident), register
// ping-pong one k-step ahead. LDS (41 KB) only for the 4-pass softmax epilogue.
// A-frag layout: row=lane&31, k=8*(lane>>5)+j. C/D: col=lane&31,
// row=(reg&3)+8*(reg>>2)+4*(lane>>5)  [m74/m101-verified].

__global__ __launch_bounds__(256, 2) void k_main_mfma(
        const unsigned short* __restrict__ hnb, const unsigned short* __restrict__ Bp,
        float* __restrict__ out) {
    __shared__ float Cs[64 * 161];
    int tid = threadIdx.x;
    int wave = tid >> 6, lane = tid & 63;
    int lo = lane & 31, hi = lane >> 5;

    // XCD swizzle: 7 col-blocks of one row-block land on one XCD
    int id = blockIdx.x;
    int xcd = id & 7, t = id >> 3;      // t = cb*16 + rr
    int cb = t >> 4;                    // 0..6
    int rr = t & 15;
    int r0 = (rr * 8 + xcd) * 256;

    const unsigned short* pa0 = hnb + (size_t)(r0 + wave * 32 + lo) * ND + hi * 8;
    const unsigned short* pa1 = pa0 + 128 * ND;
    const unsigned short* pb0 = Bp + (size_t)(cb * 160 + lo) * ND + hi * 8;

    f32x16 acc[2][5] = {};
    short8 a0[2], b0[5], a1[2], b1[5];

    // prologue: k-step 0
    a0[0] = *(const short8*)pa0;
    a0[1] = *(const short8*)pa1;
#pragma unroll
    for (int ct = 0; ct < 5; ++ct)
        b0[ct] = *(const short8*)(pb0 + (size_t)ct * 32 * ND);
    pa0 += 16; pa1 += 16; pb0 += 16;     // now at k-step 1

#pragma unroll 1
    for (int ks = 0; ks < 32; ks += 2) {
        // prefetch ks+1
        a1[0] = *(const short8*)pa0;
        a1[1] = *(const short8*)pa1;
#pragma unroll
        for (int ct = 0; ct < 5; ++ct)
            b1[ct] = *(const short8*)(pb0 + (size_t)ct * 32 * ND);
#pragma unroll
        for (int rt = 0; rt < 2; ++rt)
#pragma unroll
            for (int ct = 0; ct < 5; ++ct)
                acc[rt][ct] = __builtin_amdgcn_mfma_f32_32x32x16_bf16(
                    a0[rt], b0[ct], acc[rt][ct], 0, 0, 0);
        // prefetch ks+2 (last iter over-reads 64B into next array: in-bounds by layout)
        a0[0] = *(const short8*)(pa0 + 16);
        a0[1] = *(const short8*)(pa1 + 16);
#pragma unroll
        for (int ct = 0; ct < 5; ++ct)
            b0[ct] = *(const short8*)(pb0 + (size_t)ct * 32 * ND + 16);
#pragma unroll
        for (int rt = 0; rt < 2; ++rt)
#pragma unroll
            for (int ct = 0; ct < 5; ++ct)
                acc[rt][ct] = __builtin_amdgcn_mfma_f32_32x32x16_bf16(
                    a1[rt], b1[ct], acc[rt][ct], 0, 0, 0);
        pa0 += 32; pa1 += 32; pb0 += 32;
    }

    // 4-pass epilogue: pass p covers global rows r0+p*64 .. +63
    // wave w owns row-tile rt at global rows r0 + w*32 + rt*128
#pragma unroll 1
    for (int p = 0; p < 4; ++p) {
        __syncthreads();
        if ((wave >> 1) == (p & 1)) {
            int rt = p >> 1;
            int lrb = (wave & 1) * 32;
#pragma unroll
            for (int ct = 0; ct < 5; ++ct)
#pragma unroll
                for (int reg = 0; reg < 16; ++reg) {
                    int lr = lrb + (reg & 3) + 8 * (reg >> 2) + 4 * hi;
                    Cs[lr * 161 + ct * 32 + lo] = acc[rt][ct][reg];
                }
        }
        __syncthreads();
        int cl = tid & 15;
        int c = cb * 16 + cl;
        if (c < NC) {
#pragma unroll
            for (int q = 0; q < 4; ++q) {
                int r = (tid >> 4) + q * 16;
                float v[10];
#pragma unroll
                for (int j = 0; j < 10; ++j) v[j] = Cs[r * 161 + cl * 10 + j];
                float se = 0.f, sec = 0.f;
#pragma unroll
                for (int j = 0; j < 8; ++j) {
                    float e = __expf(v[j] * 20.0f);  // 1/SUB_T; cos<=~1 so no overflow
                    se += e; sec += e * v[j];
                }
                out[(size_t)(r0 + p * 64 + r) * NC + c] =
                    (sec / se + (v[8] + v[9])) * (1.0f / 0.07f);
            }
        }
    }
}

extern "C" void kernel_launch(void* const* d_in, const int* in_sizes, int n_in,
                              void* d_out, int out_size, void* d_ws, size_t ws_size,
                              hipStream_t stream) {
    (void)in_sizes; (void)n_in; (void)out_size; (void)ws_size;
    const float* h = (const float*)d_in[0];
    const float* protos = (const float*)d_in[1];
    float* out = (float*)d_out;

    // layout: bf16 GEMM operands first so K-loop tail over-reads stay in-bounds
    unsigned short* hnb = (unsigned short*)d_ws;            // 32768*512 bf16
    unsigned short* Bp  = hnb + (size_t)NB * ND;            // 1120*512 bf16
    float* X        = (float*)(Bp + 1120 * ND);             // 512000 (Pn|centers|bvec)
    float* centersT = X + 512000;                           // 51200  [512][100]
    float* M        = centersT + 51200;                     // 10000
    float* T1       = M + 10000;                            // 100000 [1000][100]
    float* T2       = T1 + 100000;                          // 100000 [1000][100]

    k_hn<<<NB / 4, 256, 0, stream>>>(h, hnb);
    k_prep_class<<<NC, 256, 0, stream>>>(protos, X, centersT, Bp);
    k_csbopp<<<NC, 256, 0, stream>>>(X);
    k_T1M<<<250, 256, 0, stream>>>(X, centersT, T1, M);
    k_T2neu<<<250, 256, 0, stream>>>(M, T1, T2);
    k_solveW<<<112, 256, 0, stream>>>(X, T1, T2, Bp);
    k_main_mfma<<<896, 256, 0, stream>>>(hnb, Bp, out);
}